// Round 1
// baseline (1744.517 us; speedup 1.0000x reference)
//
#include <hip/hip_runtime.h>
#include <cstddef>

// Problem constants
#define Bb 4
#define Mm 2048
#define Dd 1024
#define Nn 64
#define Pp 32
#define NP 2048   // Nn*Pp
#define BM 8192   // Bb*Mm

// Tiling
#define TS 128
#define KT 16
#define LDW 132   // TS + 4 pad to break LDS bank conflicts on transposed stores

// ---------------------------------------------------------------------------
// GEMM core macro: expects As[KT][LDW], Bs[KT][LDW] staged, accumulates 8x8
// per thread (tx = tid&15 -> col group, ty = tid>>4 -> row group).
// ---------------------------------------------------------------------------
#define GEMM_COMPUTE()                                                        \
  _Pragma("unroll")                                                           \
  for (int kk = 0; kk < KT; ++kk) {                                           \
    float4 a0 = *(const float4*)(&As[kk][ty * 8]);                            \
    float4 a1 = *(const float4*)(&As[kk][ty * 8 + 4]);                        \
    float4 b0 = *(const float4*)(&Bs[kk][tx * 8]);                            \
    float4 b1 = *(const float4*)(&Bs[kk][tx * 8 + 4]);                        \
    float a[8] = {a0.x, a0.y, a0.z, a0.w, a1.x, a1.y, a1.z, a1.w};            \
    float b[8] = {b0.x, b0.y, b0.z, b0.w, b1.x, b1.y, b1.z, b1.w};            \
    _Pragma("unroll")                                                         \
    for (int i = 0; i < 8; ++i)                                               \
      _Pragma("unroll")                                                       \
      for (int j = 0; j < 8; ++j)                                             \
        acc[i][j] = fmaf(a[i], b[j], acc[i][j]);                              \
  }

// ---------------------------------------------------------------------------
// K1: logits (BM x NP) = x (BM x Dd) @ phi (Dd x NP)
// ---------------------------------------------------------------------------
__global__ __launch_bounds__(256) void k_logits(const float* __restrict__ A,
                                                const float* __restrict__ Bm,
                                                float* __restrict__ C) {
  __shared__ float As[KT][LDW];
  __shared__ float Bs[KT][LDW];
  const int tid = threadIdx.x;
  const int tx = tid & 15, ty = tid >> 4;
  const int row0 = blockIdx.y * TS;
  const int col0 = blockIdx.x * TS;
  float acc[8][8] = {};
  for (int kt = 0; kt < Dd; kt += KT) {
#pragma unroll
    for (int it = 0; it < 2; ++it) {
      int idx = tid + it * 256;
      int r = idx >> 2;
      int kq = (idx & 3) << 2;
      float4 av = *(const float4*)(A + (row0 + r) * Dd + kt + kq);
      As[kq + 0][r] = av.x; As[kq + 1][r] = av.y;
      As[kq + 2][r] = av.z; As[kq + 3][r] = av.w;
    }
#pragma unroll
    for (int it = 0; it < 2; ++it) {
      int idx = tid + it * 256;
      int kr = idx >> 5;
      int cl = (idx & 31) << 2;
      *(float4*)(&Bs[kr][cl]) = *(const float4*)(Bm + (kt + kr) * NP + col0 + cl);
    }
    __syncthreads();
    GEMM_COMPUTE();
    __syncthreads();
  }
#pragma unroll
  for (int i = 0; i < 8; ++i) {
    float* cp = C + (row0 + ty * 8 + i) * NP + col0 + tx * 8;
    *(float4*)cp = make_float4(acc[i][0], acc[i][1], acc[i][2], acc[i][3]);
    *(float4*)(cp + 4) = make_float4(acc[i][4], acc[i][5], acc[i][6], acc[i][7]);
  }
}

// ---------------------------------------------------------------------------
// K2: softmaxes. One block per m. dispatch = softmax over b (size 4).
// combine = softmax over np (size 2048) per (b,m). combine written in-place
// over logits (block loads everything to LDS first).
// ---------------------------------------------------------------------------
__global__ __launch_bounds__(256) void k_softmax(const float* __restrict__ logits,
                                                 float* __restrict__ dispatch,
                                                 float* __restrict__ combine) {
  __shared__ float sh[Bb][NP];
  __shared__ float red[256];
  const int m = blockIdx.x;
  const int tid = threadIdx.x;
#pragma unroll
  for (int b = 0; b < Bb; ++b) {
    const float4* src = (const float4*)(logits + (b * Mm + m) * NP);
#pragma unroll
    for (int it = 0; it < 2; ++it) {
      int i = tid + it * 256;
      ((float4*)sh[b])[i] = src[i];
    }
  }
  __syncthreads();
  // dispatch: softmax across b for each np
#pragma unroll
  for (int it = 0; it < 8; ++it) {
    int np = tid + it * 256;
    float v0 = sh[0][np], v1 = sh[1][np], v2 = sh[2][np], v3 = sh[3][np];
    float mx = fmaxf(fmaxf(v0, v1), fmaxf(v2, v3));
    float e0 = __expf(v0 - mx), e1 = __expf(v1 - mx);
    float e2 = __expf(v2 - mx), e3 = __expf(v3 - mx);
    float inv = 1.0f / (e0 + e1 + e2 + e3);
    dispatch[(0 * Mm + m) * NP + np] = e0 * inv;
    dispatch[(1 * Mm + m) * NP + np] = e1 * inv;
    dispatch[(2 * Mm + m) * NP + np] = e2 * inv;
    dispatch[(3 * Mm + m) * NP + np] = e3 * inv;
  }
  // combine: per-b softmax over the 2048-slot axis
#pragma unroll
  for (int b = 0; b < Bb; ++b) {
    float lmax = -3.0e38f;
#pragma unroll
    for (int it = 0; it < 8; ++it) lmax = fmaxf(lmax, sh[b][tid + it * 256]);
    red[tid] = lmax;
    __syncthreads();
    for (int s = 128; s > 0; s >>= 1) {
      if (tid < s) red[tid] = fmaxf(red[tid], red[tid + s]);
      __syncthreads();
    }
    float mx = red[0];
    __syncthreads();
    float lsum = 0.0f;
#pragma unroll
    for (int it = 0; it < 8; ++it) lsum += __expf(sh[b][tid + it * 256] - mx);
    red[tid] = lsum;
    __syncthreads();
    for (int s = 128; s > 0; s >>= 1) {
      if (tid < s) red[tid] += red[tid + s];
      __syncthreads();
    }
    float inv = 1.0f / red[0];
    __syncthreads();
#pragma unroll
    for (int it = 0; it < 8; ++it) {
      int np = tid + it * 256;
      combine[(b * Mm + m) * NP + np] = __expf(sh[b][np] - mx) * inv;
    }
  }
}

// ---------------------------------------------------------------------------
// K3: slots[b] (NP x Dd) = dispatch[b]^T (NP x Mm) @ x[b] (Mm x Dd)
// dispatch is (Mm x NP) row-major, i.e. already K-major for the A-tile.
// ---------------------------------------------------------------------------
__global__ __launch_bounds__(256) void k_slots(const float* __restrict__ dispatch,
                                               const float* __restrict__ x,
                                               float* __restrict__ slots) {
  __shared__ float As[KT][LDW];
  __shared__ float Bs[KT][LDW];
  const int b = blockIdx.z;
  const float* A = dispatch + b * Mm * NP;
  const float* Bm = x + b * Mm * Dd;
  float* C = slots + b * NP * Dd;
  const int tid = threadIdx.x;
  const int tx = tid & 15, ty = tid >> 4;
  const int row0 = blockIdx.y * TS;  // np
  const int col0 = blockIdx.x * TS;  // d
  float acc[8][8] = {};
  for (int kt = 0; kt < Mm; kt += KT) {
#pragma unroll
    for (int it = 0; it < 2; ++it) {
      int idx = tid + it * 256;
      int kr = idx >> 5;
      int cl = (idx & 31) << 2;
      *(float4*)(&As[kr][cl]) = *(const float4*)(A + (kt + kr) * NP + row0 + cl);
    }
#pragma unroll
    for (int it = 0; it < 2; ++it) {
      int idx = tid + it * 256;
      int kr = idx >> 5;
      int cl = (idx & 31) << 2;
      *(float4*)(&Bs[kr][cl]) = *(const float4*)(Bm + (kt + kr) * Dd + col0 + cl);
    }
    __syncthreads();
    GEMM_COMPUTE();
    __syncthreads();
  }
#pragma unroll
  for (int i = 0; i < 8; ++i) {
    float* cp = C + (row0 + ty * 8 + i) * Dd + col0 + tx * 8;
    *(float4*)cp = make_float4(acc[i][0], acc[i][1], acc[i][2], acc[i][3]);
    *(float4*)(cp + 4) = make_float4(acc[i][4], acc[i][5], acc[i][6], acc[i][7]);
  }
}

// ---------------------------------------------------------------------------
// K4: per expert n: y rows (b,p) = slots rows (b,n,p,:) @ W[n] (Dd x Dd) + bias
// 128 rows exactly (Bb*Pp). grid = (Dd/TS, 1, Nn)
// ---------------------------------------------------------------------------
__global__ __launch_bounds__(256) void k_y(const float* __restrict__ slots,
                                           const float* __restrict__ W,
                                           const float* __restrict__ bias,
                                           float* __restrict__ y) {
  __shared__ float As[KT][LDW];
  __shared__ float Bs[KT][LDW];
  const int n = blockIdx.z;
  const int tid = threadIdx.x;
  const int tx = tid & 15, ty = tid >> 4;
  const int col0 = blockIdx.x * TS;
  const float* Wn = W + n * Dd * Dd;
  float acc[8][8] = {};
  for (int kt = 0; kt < Dd; kt += KT) {
#pragma unroll
    for (int it = 0; it < 2; ++it) {
      int idx = tid + it * 256;
      int r = idx >> 2;             // 0..127 = b*32 + p
      int kq = (idx & 3) << 2;
      int roff = (r >> 5) * (Nn * Pp * Dd) + n * (Pp * Dd) + (r & 31) * Dd;
      float4 av = *(const float4*)(slots + roff + kt + kq);
      As[kq + 0][r] = av.x; As[kq + 1][r] = av.y;
      As[kq + 2][r] = av.z; As[kq + 3][r] = av.w;
    }
#pragma unroll
    for (int it = 0; it < 2; ++it) {
      int idx = tid + it * 256;
      int kr = idx >> 5;
      int cl = (idx & 31) << 2;
      *(float4*)(&Bs[kr][cl]) = *(const float4*)(Wn + (kt + kr) * Dd + col0 + cl);
    }
    __syncthreads();
    GEMM_COMPUTE();
    __syncthreads();
  }
#pragma unroll
  for (int i = 0; i < 8; ++i) {
    int r = ty * 8 + i;
    int roff = (r >> 5) * (Nn * Pp * Dd) + n * (Pp * Dd) + (r & 31) * Dd;
    float* cp = y + roff + col0 + tx * 8;
    const float* bp = bias + n * Dd + col0 + tx * 8;
    *(float4*)cp = make_float4(acc[i][0] + bp[0], acc[i][1] + bp[1],
                               acc[i][2] + bp[2], acc[i][3] + bp[3]);
    *(float4*)(cp + 4) = make_float4(acc[i][4] + bp[4], acc[i][5] + bp[5],
                                     acc[i][6] + bp[6], acc[i][7] + bp[7]);
  }
}

// ---------------------------------------------------------------------------
// K5: out[b] (Mm x Dd) = combine[b] (Mm x NP) @ y[b] (NP x Dd)
// ---------------------------------------------------------------------------
__global__ __launch_bounds__(256) void k_out(const float* __restrict__ combine,
                                             const float* __restrict__ y,
                                             float* __restrict__ out) {
  __shared__ float As[KT][LDW];
  __shared__ float Bs[KT][LDW];
  const int b = blockIdx.z;
  const float* A = combine + b * Mm * NP;
  const float* Bm = y + b * NP * Dd;
  float* C = out + b * Mm * Dd;
  const int tid = threadIdx.x;
  const int tx = tid & 15, ty = tid >> 4;
  const int row0 = blockIdx.y * TS;  // m
  const int col0 = blockIdx.x * TS;  // d
  float acc[8][8] = {};
  for (int kt = 0; kt < NP; kt += KT) {
#pragma unroll
    for (int it = 0; it < 2; ++it) {
      int idx = tid + it * 256;
      int r = idx >> 2;
      int kq = (idx & 3) << 2;
      float4 av = *(const float4*)(A + (row0 + r) * NP + kt + kq);
      As[kq + 0][r] = av.x; As[kq + 1][r] = av.y;
      As[kq + 2][r] = av.z; As[kq + 3][r] = av.w;
    }
#pragma unroll
    for (int it = 0; it < 2; ++it) {
      int idx = tid + it * 256;
      int kr = idx >> 5;
      int cl = (idx & 31) << 2;
      *(float4*)(&Bs[kr][cl]) = *(const float4*)(Bm + (kt + kr) * Dd + col0 + cl);
    }
    __syncthreads();
    GEMM_COMPUTE();
    __syncthreads();
  }
#pragma unroll
  for (int i = 0; i < 8; ++i) {
    float* cp = C + (row0 + ty * 8 + i) * Dd + col0 + tx * 8;
    *(float4*)cp = make_float4(acc[i][0], acc[i][1], acc[i][2], acc[i][3]);
    *(float4*)(cp + 4) = make_float4(acc[i][4], acc[i][5], acc[i][6], acc[i][7]);
  }
}

// ---------------------------------------------------------------------------
extern "C" void kernel_launch(void* const* d_in, const int* in_sizes, int n_in,
                              void* d_out, int out_size, void* d_ws, size_t ws_size,
                              hipStream_t stream) {
  const float* x    = (const float*)d_in[0];  // (B, M, D)
  const float* phi  = (const float*)d_in[1];  // (D, N, P)
  const float* W    = (const float*)d_in[2];  // (N, D, D)
  const float* bias = (const float*)d_in[3];  // (N, D)
  float* out = (float*)d_out;                 // (B, M, D)

  float* ws = (float*)d_ws;
  // Workspace layout (floats):
  //   [0, 16M)        logits, overwritten in-place by combine
  //   [16M, 32M)      dispatch; first 8M floats reused for y after k_slots
  //   [32M, 40M)      slots
  float* logits   = ws;                       // 16777216 floats (= combine)
  float* dispatch = ws + 16777216;            // 16777216 floats
  float* slots    = ws + 33554432;            // 8388608 floats
  float* y        = dispatch;                 // reuse: dispatch dead after k_slots

  k_logits <<<dim3(NP / TS, BM / TS), 256, 0, stream>>>(x, phi, logits);
  k_softmax<<<Mm, 256, 0, stream>>>(logits, dispatch, logits);
  k_slots  <<<dim3(Dd / TS, NP / TS, Bb), 256, 0, stream>>>(dispatch, x, slots);
  k_y      <<<dim3(Dd / TS, 1, Nn), 256, 0, stream>>>(slots, W, bias, y);
  k_out    <<<dim3(Dd / TS, Mm / TS, Bb), 256, 0, stream>>>(logits, y, out);
}

// Round 2
// 629.425 us; speedup vs baseline: 2.7716x; 2.7716x over previous
//
#include <hip/hip_runtime.h>
#include <cstddef>

#define Bb 4
#define Mm 2048
#define Dd 1024
#define Nn 64
#define Pp 32
#define NP 2048
#define BM 8192

typedef __attribute__((ext_vector_type(4))) float v4f;
typedef __attribute__((ext_vector_type(8))) short v8s;

__device__ inline unsigned short f2b(float f) {
  union { float f; unsigned u; } v; v.f = f;
  unsigned r = v.u + 0x7fff + ((v.u >> 16) & 1);
  return (unsigned short)(r >> 16);
}

__device__ inline void gld16(const void* g, void* l) {
  __builtin_amdgcn_global_load_lds(
      (const __attribute__((address_space(1))) unsigned*)g,
      (__attribute__((address_space(3))) unsigned*)l, 16, 0, 0);
}

// ---------------------------------------------------------------------------
// flat fp32 -> bf16 convert (8 elements/thread)
// ---------------------------------------------------------------------------
__global__ __launch_bounds__(256) void k_cvt(const float* __restrict__ in,
                                             unsigned short* __restrict__ out) {
  size_t i = (size_t)blockIdx.x * 256 + threadIdx.x;
  float4 v0 = ((const float4*)in)[2 * i];
  float4 v1 = ((const float4*)in)[2 * i + 1];
  uint4 o;
  o.x = (unsigned)f2b(v0.x) | ((unsigned)f2b(v0.y) << 16);
  o.y = (unsigned)f2b(v0.z) | ((unsigned)f2b(v0.w) << 16);
  o.z = (unsigned)f2b(v1.x) | ((unsigned)f2b(v1.y) << 16);
  o.w = (unsigned)f2b(v1.z) | ((unsigned)f2b(v1.w) << 16);
  *(uint4*)&out[8 * i] = o;
}

// ---------------------------------------------------------------------------
// tiled transpose fp32 -> bf16 : in [R][C] -> out [C][R], batched
// ---------------------------------------------------------------------------
__global__ __launch_bounds__(256) void k_tr_f2b(const float* __restrict__ in, size_t sin_,
                                                unsigned short* __restrict__ out, size_t sout,
                                                int R, int C) {
  __shared__ unsigned short t[32][33];
  const int r0 = blockIdx.y * 32, c0 = blockIdx.x * 32;
  const float* ib = in + (size_t)blockIdx.z * sin_;
  unsigned short* ob = out + (size_t)blockIdx.z * sout;
  const int tr = threadIdx.x >> 3;
  const int tc = (threadIdx.x & 7) * 4;
  float4 v = *(const float4*)&ib[(size_t)(r0 + tr) * C + c0 + tc];
  t[tr][tc + 0] = f2b(v.x); t[tr][tc + 1] = f2b(v.y);
  t[tr][tc + 2] = f2b(v.z); t[tr][tc + 3] = f2b(v.w);
  __syncthreads();
  ushort4 o;
  o.x = t[tc + 0][tr]; o.y = t[tc + 1][tr];
  o.z = t[tc + 2][tr]; o.w = t[tc + 3][tr];
  *(ushort4*)&ob[(size_t)(c0 + tr) * R + r0 + tc] = o;
}

// bf16 -> bf16 variant
__global__ __launch_bounds__(256) void k_tr_b2b(const unsigned short* __restrict__ in, size_t sin_,
                                                unsigned short* __restrict__ out, size_t sout,
                                                int R, int C) {
  __shared__ unsigned short t[32][33];
  const int r0 = blockIdx.y * 32, c0 = blockIdx.x * 32;
  const unsigned short* ib = in + (size_t)blockIdx.z * sin_;
  unsigned short* ob = out + (size_t)blockIdx.z * sout;
  const int tr = threadIdx.x >> 3;
  const int tc = (threadIdx.x & 7) * 4;
  ushort4 v = *(const ushort4*)&ib[(size_t)(r0 + tr) * C + c0 + tc];
  t[tr][tc + 0] = v.x; t[tr][tc + 1] = v.y;
  t[tr][tc + 2] = v.z; t[tr][tc + 3] = v.w;
  __syncthreads();
  ushort4 o;
  o.x = t[tc + 0][tr]; o.y = t[tc + 1][tr];
  o.z = t[tc + 2][tr]; o.w = t[tc + 3][tr];
  *(ushort4*)&ob[(size_t)(c0 + tr) * R + r0 + tc] = o;
}

// ---------------------------------------------------------------------------
// m97-style bf16 MFMA GEMM: C[M,N] = A[M,K] @ B^T[N,K]   (both K-contiguous)
// 128x128 tile, BK=32, 4 waves, 4x4 16x16x32 MFMA tiles per wave.
// ---------------------------------------------------------------------------
template <int OUT_BF16>
__global__ __launch_bounds__(256) void k_gemm(const unsigned short* __restrict__ A, size_t sA,
                                              const unsigned short* __restrict__ B, size_t sB,
                                              void* __restrict__ C, size_t sC,
                                              int M, int N, int K) {
  __shared__ unsigned short As[128][32];
  __shared__ unsigned short Bs[128][32];
  const int tid = threadIdx.x;
  const int wv = tid >> 6, ln = tid & 63;
  const int wm = wv & 1, wn = wv >> 1;
  const int row0 = blockIdx.y * 128, col0 = blockIdx.x * 128;
  const unsigned short* Ab = A + (size_t)blockIdx.z * sA + (size_t)row0 * K;
  const unsigned short* Bbp = B + (size_t)blockIdx.z * sB + (size_t)col0 * K;
  const int sr = ln >> 2;         // staging row within 16
  const int sc = (ln & 3) * 8;    // staging k-element offset
  const int fr = ln & 15, fc = (ln >> 4) * 8;
  v4f acc[4][4];
#pragma unroll
  for (int i = 0; i < 4; ++i)
#pragma unroll
    for (int j = 0; j < 4; ++j) { v4f z = {0.f, 0.f, 0.f, 0.f}; acc[i][j] = z; }

  for (int kt = 0; kt < K; kt += 32) {
    __syncthreads();
    gld16(Ab + (size_t)(32 * wv + sr) * K + kt + sc,      &As[32 * wv][0]);
    gld16(Ab + (size_t)(32 * wv + 16 + sr) * K + kt + sc, &As[32 * wv + 16][0]);
    gld16(Bbp + (size_t)(32 * wv + sr) * K + kt + sc,      &Bs[32 * wv][0]);
    gld16(Bbp + (size_t)(32 * wv + 16 + sr) * K + kt + sc, &Bs[32 * wv + 16][0]);
    __syncthreads();
    v8s a[4], b[4];
#pragma unroll
    for (int i = 0; i < 4; ++i) a[i] = *(const v8s*)&As[64 * wm + 16 * i + fr][fc];
#pragma unroll
    for (int j = 0; j < 4; ++j) b[j] = *(const v8s*)&Bs[64 * wn + 16 * j + fr][fc];
#pragma unroll
    for (int i = 0; i < 4; ++i)
#pragma unroll
      for (int j = 0; j < 4; ++j)
        acc[i][j] = __builtin_amdgcn_mfma_f32_16x16x32_bf16(a[i], b[j], acc[i][j], 0, 0, 0);
  }
  const int er = (ln >> 4) * 4, ec = ln & 15;
#pragma unroll
  for (int i = 0; i < 4; ++i)
#pragma unroll
    for (int j = 0; j < 4; ++j) {
      int r = row0 + 64 * wm + 16 * i + er;
      int c = col0 + 64 * wn + 16 * j + ec;
      if (OUT_BF16) {
        unsigned short* Cp = (unsigned short*)C + (size_t)blockIdx.z * sC + (size_t)r * N + c;
#pragma unroll
        for (int q = 0; q < 4; ++q) Cp[(size_t)q * N] = f2b(acc[i][j][q]);
      } else {
        float* Cp = (float*)C + (size_t)blockIdx.z * sC + (size_t)r * N + c;
#pragma unroll
        for (int q = 0; q < 4; ++q) Cp[(size_t)q * N] = acc[i][j][q];
      }
    }
}

// ---------------------------------------------------------------------------
// softmaxes: one block per m. dispatch = softmax over b (4); combine = softmax
// over np (2048). Both written bf16 in natural [b][m][np] layout.
// ---------------------------------------------------------------------------
__global__ __launch_bounds__(256) void k_softmax(const float* __restrict__ logits,
                                                 unsigned short* __restrict__ dispatch,
                                                 unsigned short* __restrict__ combine) {
  __shared__ float sh[Bb][NP];
  __shared__ float red[256];
  const int m = blockIdx.x;
  const int tid = threadIdx.x;
#pragma unroll
  for (int b = 0; b < Bb; ++b) {
    const float4* src = (const float4*)(logits + ((size_t)b * Mm + m) * NP);
#pragma unroll
    for (int it = 0; it < 2; ++it) ((float4*)sh[b])[tid + it * 256] = src[tid + it * 256];
  }
  __syncthreads();
#pragma unroll
  for (int it = 0; it < 8; ++it) {
    int np = tid + it * 256;
    float v0 = sh[0][np], v1 = sh[1][np], v2 = sh[2][np], v3 = sh[3][np];
    float mx = fmaxf(fmaxf(v0, v1), fmaxf(v2, v3));
    float e0 = __expf(v0 - mx), e1 = __expf(v1 - mx);
    float e2 = __expf(v2 - mx), e3 = __expf(v3 - mx);
    float inv = 1.0f / (e0 + e1 + e2 + e3);
    dispatch[((size_t)0 * Mm + m) * NP + np] = f2b(e0 * inv);
    dispatch[((size_t)1 * Mm + m) * NP + np] = f2b(e1 * inv);
    dispatch[((size_t)2 * Mm + m) * NP + np] = f2b(e2 * inv);
    dispatch[((size_t)3 * Mm + m) * NP + np] = f2b(e3 * inv);
  }
#pragma unroll
  for (int b = 0; b < Bb; ++b) {
    float lmax = -3.0e38f;
#pragma unroll
    for (int it = 0; it < 8; ++it) lmax = fmaxf(lmax, sh[b][tid + it * 256]);
    red[tid] = lmax;
    __syncthreads();
    for (int s = 128; s > 0; s >>= 1) {
      if (tid < s) red[tid] = fmaxf(red[tid], red[tid + s]);
      __syncthreads();
    }
    float mx = red[0];
    __syncthreads();
    float lsum = 0.0f;
#pragma unroll
    for (int it = 0; it < 8; ++it) lsum += __expf(sh[b][tid + it * 256] - mx);
    red[tid] = lsum;
    __syncthreads();
    for (int s = 128; s > 0; s >>= 1) {
      if (tid < s) red[tid] += red[tid + s];
      __syncthreads();
    }
    float inv = 1.0f / red[0];
    __syncthreads();
#pragma unroll
    for (int it = 0; it < 8; ++it) {
      int np = tid + it * 256;
      combine[((size_t)b * Mm + m) * NP + np] = f2b(__expf(sh[b][np] - mx) * inv);
    }
  }
}

// ---------------------------------------------------------------------------
// k_y: per expert n: y[(b,p), e] = slots[(b,n,p), :] @ W[n][:, e] + bias[n][e]
// A (slots) bf16 via global_load_lds; B (W fp32) transposed on the fly into
// padded LDS [128][40]. M=128 exactly. Output y bf16 natural [b][np][e].
// ---------------------------------------------------------------------------
__global__ __launch_bounds__(256) void k_y_mfma(const unsigned short* __restrict__ slots,
                                                const float* __restrict__ W,
                                                const float* __restrict__ bias,
                                                unsigned short* __restrict__ y) {
  __shared__ unsigned short As[128][32];
  __shared__ unsigned short Bs[128][40];  // +8 pad: 80B rows, 16B-aligned, spreads banks
  const int n = blockIdx.z;
  const int col0 = blockIdx.x * 128;
  const int tid = threadIdx.x;
  const int wv = tid >> 6, ln = tid & 63;
  const int wm = wv & 1, wn = wv >> 1;
  const int sr = ln >> 2, sc = (ln & 3) * 8;
  const int fr = ln & 15, fc = (ln >> 4) * 8;
  const float* Wn = W + (size_t)n * Dd * Dd;
  v4f acc[4][4];
#pragma unroll
  for (int i = 0; i < 4; ++i)
#pragma unroll
    for (int j = 0; j < 4; ++j) { v4f z = {0.f, 0.f, 0.f, 0.f}; acc[i][j] = z; }

  const int te = tid & 127;          // e within tile for B staging
  const int tks = (tid >> 7) * 4;    // k segment

  for (int kt = 0; kt < Dd; kt += 32) {
    __syncthreads();
    {
      int r1 = 32 * wv + sr;
      int r2 = r1 + 16;
      size_t g1 = ((size_t)(r1 >> 5) * NP + n * Pp + (r1 & 31)) * Dd;
      size_t g2 = ((size_t)(r2 >> 5) * NP + n * Pp + (r2 & 31)) * Dd;
      gld16(slots + g1 + kt + sc, &As[32 * wv][0]);
      gld16(slots + g2 + kt + sc, &As[32 * wv + 16][0]);
    }
#pragma unroll
    for (int kk = 0; kk < 4; ++kk) {
      int k0 = kk * 8 + tks;
      float f0 = Wn[(size_t)(kt + k0 + 0) * Dd + col0 + te];
      float f1 = Wn[(size_t)(kt + k0 + 1) * Dd + col0 + te];
      float f2 = Wn[(size_t)(kt + k0 + 2) * Dd + col0 + te];
      float f3 = Wn[(size_t)(kt + k0 + 3) * Dd + col0 + te];
      unsigned long long pk = (unsigned long long)f2b(f0) |
                              ((unsigned long long)f2b(f1) << 16) |
                              ((unsigned long long)f2b(f2) << 32) |
                              ((unsigned long long)f2b(f3) << 48);
      *(unsigned long long*)&Bs[te][k0] = pk;
    }
    __syncthreads();
    v8s a[4], b[4];
#pragma unroll
    for (int i = 0; i < 4; ++i) a[i] = *(const v8s*)&As[64 * wm + 16 * i + fr][fc];
#pragma unroll
    for (int j = 0; j < 4; ++j) b[j] = *(const v8s*)&Bs[64 * wn + 16 * j + fr][fc];
#pragma unroll
    for (int i = 0; i < 4; ++i)
#pragma unroll
      for (int j = 0; j < 4; ++j)
        acc[i][j] = __builtin_amdgcn_mfma_f32_16x16x32_bf16(a[i], b[j], acc[i][j], 0, 0, 0);
  }
  const int er = (ln >> 4) * 4, ec = ln & 15;
  float bv[4];
#pragma unroll
  for (int j = 0; j < 4; ++j) bv[j] = bias[(size_t)n * Dd + col0 + 64 * wn + 16 * j + ec];
#pragma unroll
  for (int i = 0; i < 4; ++i)
#pragma unroll
    for (int j = 0; j < 4; ++j) {
      int c = col0 + 64 * wn + 16 * j + ec;
#pragma unroll
      for (int q = 0; q < 4; ++q) {
        int r = 64 * wm + 16 * i + er + q;
        size_t row = (size_t)(r >> 5) * NP + n * Pp + (r & 31);
        y[row * Dd + c] = f2b(acc[i][j][q] + bv[j]);
      }
    }
}

// ---------------------------------------------------------------------------
extern "C" void kernel_launch(void* const* d_in, const int* in_sizes, int n_in,
                              void* d_out, int out_size, void* d_ws, size_t ws_size,
                              hipStream_t stream) {
  const float* x    = (const float*)d_in[0];
  const float* phi  = (const float*)d_in[1];
  const float* W    = (const float*)d_in[2];
  const float* bias = (const float*)d_in[3];
  float* out = (float*)d_out;
  char* ws = (char*)d_ws;

  // Workspace (byte offsets), liveness-aliased, total 152 MB (<160 MB proven):
  //  [0,67M)        logits fp32      -> then dispT bf16 [0,33.5M) + slots bf16 [33.5M,50.3M)
  //                                   -> then y bf16 [0,16.7M) + yT bf16 [16.7M,33.5M)
  //  [67M,100.7M)   dispatch bf16
  //  [100.7M,134.2M) combine bf16
  //  [134.2M,151M)  xb bf16          -> then xT bf16 (after k_logits)
  //  [151M,159.4M)  phiT bf16
  float*          logits = (float*)(ws);
  unsigned short* dispT  = (unsigned short*)(ws);
  unsigned short* slots  = (unsigned short*)(ws + 33554432);
  unsigned short* y_b    = (unsigned short*)(ws);
  unsigned short* yT     = (unsigned short*)(ws + 16777216);
  unsigned short* disp_b = (unsigned short*)(ws + 67108864);
  unsigned short* comb_b = (unsigned short*)(ws + 100663296);
  unsigned short* xb     = (unsigned short*)(ws + 134217728);
  unsigned short* xT     = (unsigned short*)(ws + 134217728);
  unsigned short* phiT   = (unsigned short*)(ws + 150994944);

  k_cvt<<<4096, 256, 0, stream>>>(x, xb);
  k_tr_f2b<<<dim3(64, 32, 1), 256, 0, stream>>>(phi, 0, phiT, 0, Dd, NP);
  k_gemm<0><<<dim3(16, 64, 1), 256, 0, stream>>>(xb, 0, phiT, 0, logits, 0, BM, NP, Dd);
  k_tr_f2b<<<dim3(32, 64, Bb), 256, 0, stream>>>(x, (size_t)Mm * Dd, xT, (size_t)Dd * Mm, Mm, Dd);
  k_softmax<<<Mm, 256, 0, stream>>>(logits, disp_b, comb_b);
  k_tr_b2b<<<dim3(64, 64, Bb), 256, 0, stream>>>(disp_b, (size_t)Mm * NP, dispT, (size_t)NP * Mm, Mm, NP);
  k_gemm<1><<<dim3(8, 16, Bb), 256, 0, stream>>>(dispT, (size_t)NP * Mm, xT, (size_t)Dd * Mm,
                                                 slots, (size_t)NP * Dd, NP, Dd, Mm);
  k_y_mfma<<<dim3(8, 1, Nn), 256, 0, stream>>>(slots, W, bias, y_b);
  k_tr_b2b<<<dim3(32, 64, Bb), 256, 0, stream>>>(y_b, (size_t)NP * Dd, yT, (size_t)Dd * NP, NP, Dd);
  k_gemm<0><<<dim3(8, 16, Bb), 256, 0, stream>>>(comb_b, (size_t)Mm * NP, yT, (size_t)Dd * NP,
                                                 out, (size_t)Mm * Dd, Mm, Dd, NP);
}

// Round 3
// 627.160 us; speedup vs baseline: 2.7816x; 1.0036x over previous
//
#include <hip/hip_runtime.h>
#include <hip/hip_bf16.h>
#include <cstddef>

#define Bb 4
#define Mm 2048
#define Dd 1024
#define Nn 64
#define Pp 32
#define NP 2048
#define BM 8192

typedef __attribute__((ext_vector_type(4))) float v4f;
typedef __attribute__((ext_vector_type(8))) short v8s;

__device__ inline unsigned short f2b(float f) {
  union { float f; unsigned u; } v; v.f = f;
  unsigned r = v.u + 0x7fff + ((v.u >> 16) & 1);
  return (unsigned short)(r >> 16);
}

__device__ inline void gld16(const void* g, void* l) {
  __builtin_amdgcn_global_load_lds(
      (const __attribute__((address_space(1))) unsigned*)g,
      (__attribute__((address_space(3))) unsigned*)l, 16, 0, 0);
}

// ---------------------------------------------------------------------------
// k_xprep: one pass over x. Writes xb (bf16, [b][m][d]) and xT (bf16, [b][d][m]).
// ---------------------------------------------------------------------------
__global__ __launch_bounds__(256) void k_xprep(const float* __restrict__ x,
                                               unsigned short* __restrict__ xb,
                                               unsigned short* __restrict__ xT) {
  __shared__ unsigned short t[32][33];
  const int b = blockIdx.z;
  const int r0 = blockIdx.y * 32;   // m
  const int c0 = blockIdx.x * 32;   // d
  const float* ib = x + (size_t)b * Mm * Dd;
  const int tr = threadIdx.x >> 3;
  const int tc = (threadIdx.x & 7) * 4;
  float4 v = *(const float4*)&ib[(size_t)(r0 + tr) * Dd + c0 + tc];
  ushort4 s;
  s.x = f2b(v.x); s.y = f2b(v.y); s.z = f2b(v.z); s.w = f2b(v.w);
  *(ushort4*)&xb[(size_t)b * Mm * Dd + (size_t)(r0 + tr) * Dd + c0 + tc] = s;
  t[tr][tc + 0] = s.x; t[tr][tc + 1] = s.y;
  t[tr][tc + 2] = s.z; t[tr][tc + 3] = s.w;
  __syncthreads();
  ushort4 o;
  o.x = t[tc + 0][tr]; o.y = t[tc + 1][tr];
  o.z = t[tc + 2][tr]; o.w = t[tc + 3][tr];
  *(ushort4*)&xT[(size_t)b * Dd * Mm + (size_t)(c0 + tr) * Mm + r0 + tc] = o;
}

// ---------------------------------------------------------------------------
// tiled transpose fp32 -> bf16 : in [R][C] -> out [C][R] (for phi)
// ---------------------------------------------------------------------------
__global__ __launch_bounds__(256) void k_tr_f2b(const float* __restrict__ in,
                                                unsigned short* __restrict__ out,
                                                int R, int C) {
  __shared__ unsigned short t[32][33];
  const int r0 = blockIdx.y * 32, c0 = blockIdx.x * 32;
  const int tr = threadIdx.x >> 3;
  const int tc = (threadIdx.x & 7) * 4;
  float4 v = *(const float4*)&in[(size_t)(r0 + tr) * C + c0 + tc];
  t[tr][tc + 0] = f2b(v.x); t[tr][tc + 1] = f2b(v.y);
  t[tr][tc + 2] = f2b(v.z); t[tr][tc + 3] = f2b(v.w);
  __syncthreads();
  ushort4 o;
  o.x = t[tc + 0][tr]; o.y = t[tc + 1][tr];
  o.z = t[tc + 2][tr]; o.w = t[tc + 3][tr];
  *(ushort4*)&out[(size_t)(c0 + tr) * R + r0 + tc] = o;
}

// bf16 -> bf16 batched transpose
__global__ __launch_bounds__(256) void k_tr_b2b(const unsigned short* __restrict__ in, size_t sin_,
                                                unsigned short* __restrict__ out, size_t sout,
                                                int R, int C) {
  __shared__ unsigned short t[32][33];
  const int r0 = blockIdx.y * 32, c0 = blockIdx.x * 32;
  const unsigned short* ib = in + (size_t)blockIdx.z * sin_;
  unsigned short* ob = out + (size_t)blockIdx.z * sout;
  const int tr = threadIdx.x >> 3;
  const int tc = (threadIdx.x & 7) * 4;
  ushort4 v = *(const ushort4*)&ib[(size_t)(r0 + tr) * C + c0 + tc];
  t[tr][tc + 0] = v.x; t[tr][tc + 1] = v.y;
  t[tr][tc + 2] = v.z; t[tr][tc + 3] = v.w;
  __syncthreads();
  ushort4 o;
  o.x = t[tc + 0][tr]; o.y = t[tc + 1][tr];
  o.z = t[tc + 2][tr]; o.w = t[tc + 3][tr];
  *(ushort4*)&ob[(size_t)(c0 + tr) * R + r0 + tc] = o;
}

// ---------------------------------------------------------------------------
// m97-style bf16 MFMA GEMM: C[M,N] = A[M,K] @ B^T[N,K]   (both K-contiguous)
// ---------------------------------------------------------------------------
template <int OUT_BF16>
__global__ __launch_bounds__(256) void k_gemm(const unsigned short* __restrict__ A, size_t sA,
                                              const unsigned short* __restrict__ B, size_t sB,
                                              void* __restrict__ C, size_t sC,
                                              int M, int N, int K) {
  __shared__ unsigned short As[128][32];
  __shared__ unsigned short Bs[128][32];
  const int tid = threadIdx.x;
  const int wv = tid >> 6, ln = tid & 63;
  const int wm = wv & 1, wn = wv >> 1;
  const int row0 = blockIdx.y * 128, col0 = blockIdx.x * 128;
  const unsigned short* Ab = A + (size_t)blockIdx.z * sA + (size_t)row0 * K;
  const unsigned short* Bbp = B + (size_t)blockIdx.z * sB + (size_t)col0 * K;
  const int sr = ln >> 2;
  const int sc = (ln & 3) * 8;
  const int fr = ln & 15, fc = (ln >> 4) * 8;
  v4f acc[4][4];
#pragma unroll
  for (int i = 0; i < 4; ++i)
#pragma unroll
    for (int j = 0; j < 4; ++j) { v4f z = {0.f, 0.f, 0.f, 0.f}; acc[i][j] = z; }

  for (int kt = 0; kt < K; kt += 32) {
    __syncthreads();
    gld16(Ab + (size_t)(32 * wv + sr) * K + kt + sc,      &As[32 * wv][0]);
    gld16(Ab + (size_t)(32 * wv + 16 + sr) * K + kt + sc, &As[32 * wv + 16][0]);
    gld16(Bbp + (size_t)(32 * wv + sr) * K + kt + sc,      &Bs[32 * wv][0]);
    gld16(Bbp + (size_t)(32 * wv + 16 + sr) * K + kt + sc, &Bs[32 * wv + 16][0]);
    __syncthreads();
    v8s a[4], b[4];
#pragma unroll
    for (int i = 0; i < 4; ++i) a[i] = *(const v8s*)&As[64 * wm + 16 * i + fr][fc];
#pragma unroll
    for (int j = 0; j < 4; ++j) b[j] = *(const v8s*)&Bs[64 * wn + 16 * j + fr][fc];
#pragma unroll
    for (int i = 0; i < 4; ++i)
#pragma unroll
      for (int j = 0; j < 4; ++j)
        acc[i][j] = __builtin_amdgcn_mfma_f32_16x16x32_bf16(a[i], b[j], acc[i][j], 0, 0, 0);
  }
  const int er = (ln >> 4) * 4, ec = ln & 15;
#pragma unroll
  for (int i = 0; i < 4; ++i)
#pragma unroll
    for (int j = 0; j < 4; ++j) {
      int r = row0 + 64 * wm + 16 * i + er;
      int c = col0 + 64 * wn + 16 * j + ec;
      if (OUT_BF16) {
        unsigned short* Cp = (unsigned short*)C + (size_t)blockIdx.z * sC + (size_t)r * N + c;
#pragma unroll
        for (int q = 0; q < 4; ++q) Cp[(size_t)q * N] = f2b(acc[i][j][q]);
      } else {
        float* Cp = (float*)C + (size_t)blockIdx.z * sC + (size_t)r * N + c;
#pragma unroll
        for (int q = 0; q < 4; ++q) Cp[(size_t)q * N] = acc[i][j][q];
      }
    }
}

// ---------------------------------------------------------------------------
// softmaxes (shuffle-reduce version). One block per m.
// ---------------------------------------------------------------------------
__global__ __launch_bounds__(256) void k_softmax(const float* __restrict__ logits,
                                                 unsigned short* __restrict__ dispatch,
                                                 unsigned short* __restrict__ combine) {
  __shared__ float sh[Bb][NP];
  __shared__ float redm[Bb][4];
  __shared__ float reds[Bb][4];
  const int m = blockIdx.x;
  const int tid = threadIdx.x;
  const int wv = tid >> 6, ln = tid & 63;
#pragma unroll
  for (int b = 0; b < Bb; ++b) {
    const float4* src = (const float4*)(logits + ((size_t)b * Mm + m) * NP);
#pragma unroll
    for (int it = 0; it < 2; ++it) ((float4*)sh[b])[tid + it * 256] = src[tid + it * 256];
  }
  __syncthreads();
  // dispatch: softmax across b
#pragma unroll
  for (int it = 0; it < 8; ++it) {
    int np = tid + it * 256;
    float v0 = sh[0][np], v1 = sh[1][np], v2 = sh[2][np], v3 = sh[3][np];
    float mx = fmaxf(fmaxf(v0, v1), fmaxf(v2, v3));
    float e0 = __expf(v0 - mx), e1 = __expf(v1 - mx);
    float e2 = __expf(v2 - mx), e3 = __expf(v3 - mx);
    float inv = 1.0f / (e0 + e1 + e2 + e3);
    dispatch[((size_t)0 * Mm + m) * NP + np] = f2b(e0 * inv);
    dispatch[((size_t)1 * Mm + m) * NP + np] = f2b(e1 * inv);
    dispatch[((size_t)2 * Mm + m) * NP + np] = f2b(e2 * inv);
    dispatch[((size_t)3 * Mm + m) * NP + np] = f2b(e3 * inv);
  }
  // combine: per-b softmax over np
#pragma unroll
  for (int b = 0; b < Bb; ++b) {
    float lmax = -3.0e38f;
#pragma unroll
    for (int it = 0; it < 8; ++it) lmax = fmaxf(lmax, sh[b][tid + it * 256]);
#pragma unroll
    for (int o = 32; o > 0; o >>= 1) lmax = fmaxf(lmax, __shfl_xor(lmax, o, 64));
    if (ln == 0) redm[b][wv] = lmax;
    __syncthreads();
    float mx = fmaxf(fmaxf(redm[b][0], redm[b][1]), fmaxf(redm[b][2], redm[b][3]));
    float lsum = 0.0f;
#pragma unroll
    for (int it = 0; it < 8; ++it) lsum += __expf(sh[b][tid + it * 256] - mx);
#pragma unroll
    for (int o = 32; o > 0; o >>= 1) lsum += __shfl_xor(lsum, o, 64);
    if (ln == 0) reds[b][wv] = lsum;
    __syncthreads();
    float inv = 1.0f / (reds[b][0] + reds[b][1] + reds[b][2] + reds[b][3]);
#pragma unroll
    for (int it = 0; it < 8; ++it) {
      int np = tid + it * 256;
      combine[((size_t)b * Mm + m) * NP + np] = f2b(__expf(sh[b][np] - mx) * inv);
    }
  }
}

// ---------------------------------------------------------------------------
// k_y: per expert n: y[(b,p), e] = slots[(b,n,p), :] @ W[n][:, e] + bias[n][e]
// W staged via float4 loads + packed RTN cvt + 4B LDS writes (k-pairs).
// ---------------------------------------------------------------------------
__global__ __launch_bounds__(256) void k_y_mfma(const unsigned short* __restrict__ slots,
                                                const float* __restrict__ W,
                                                const float* __restrict__ bias,
                                                unsigned short* __restrict__ y) {
  __shared__ unsigned short As[128][32];
  __shared__ unsigned short Bs[128][40];
  const int n = blockIdx.z;
  const int col0 = blockIdx.x * 128;
  const int tid = threadIdx.x;
  const int wv = tid >> 6, ln = tid & 63;
  const int wm = wv & 1, wn = wv >> 1;
  const int sr = ln >> 2, sc = (ln & 3) * 8;
  const int fr = ln & 15, fc = (ln >> 4) * 8;
  const float* Wn = W + (size_t)n * Dd * Dd;
  v4f acc[4][4];
#pragma unroll
  for (int i = 0; i < 4; ++i)
#pragma unroll
    for (int j = 0; j < 4; ++j) { v4f z = {0.f, 0.f, 0.f, 0.f}; acc[i][j] = z; }

  for (int kt = 0; kt < Dd; kt += 32) {
    __syncthreads();
    {
      int r1 = 32 * wv + sr;
      int r2 = r1 + 16;
      size_t g1 = ((size_t)(r1 >> 5) * NP + n * Pp + (r1 & 31)) * Dd;
      size_t g2 = ((size_t)(r2 >> 5) * NP + n * Pp + (r2 & 31)) * Dd;
      gld16(slots + g1 + kt + sc, &As[32 * wv][0]);
      gld16(slots + g2 + kt + sc, &As[32 * wv + 16][0]);
    }
    // W tile: 32 k-rows x 128 e-cols. Each thread: 2 k-adjacent float4 pairs.
#pragma unroll
    for (int it = 0; it < 2; ++it) {
      int idx = tid + it * 256;
      int k = (idx >> 5) * 2;
      int eseg = (idx & 31) * 4;
      const float* wp = &Wn[(size_t)(kt + k) * Dd + col0 + eseg];
      float4 r0 = *(const float4*)wp;
      float4 r1 = *(const float4*)(wp + Dd);
      *(__hip_bfloat162*)&Bs[eseg + 0][k] = __float22bfloat162_rn(float2{r0.x, r1.x});
      *(__hip_bfloat162*)&Bs[eseg + 1][k] = __float22bfloat162_rn(float2{r0.y, r1.y});
      *(__hip_bfloat162*)&Bs[eseg + 2][k] = __float22bfloat162_rn(float2{r0.z, r1.z});
      *(__hip_bfloat162*)&Bs[eseg + 3][k] = __float22bfloat162_rn(float2{r0.w, r1.w});
    }
    __syncthreads();
    v8s a[4], b[4];
#pragma unroll
    for (int i = 0; i < 4; ++i) a[i] = *(const v8s*)&As[64 * wm + 16 * i + fr][fc];
#pragma unroll
    for (int j = 0; j < 4; ++j) b[j] = *(const v8s*)&Bs[64 * wn + 16 * j + fr][fc];
#pragma unroll
    for (int i = 0; i < 4; ++i)
#pragma unroll
      for (int j = 0; j < 4; ++j)
        acc[i][j] = __builtin_amdgcn_mfma_f32_16x16x32_bf16(a[i], b[j], acc[i][j], 0, 0, 0);
  }
  const int er = (ln >> 4) * 4, ec = ln & 15;
  float bv[4];
#pragma unroll
  for (int j = 0; j < 4; ++j) bv[j] = bias[(size_t)n * Dd + col0 + 64 * wn + 16 * j + ec];
#pragma unroll
  for (int i = 0; i < 4; ++i)
#pragma unroll
    for (int j = 0; j < 4; ++j) {
      int c = col0 + 64 * wn + 16 * j + ec;
#pragma unroll
      for (int q = 0; q < 4; ++q) {
        int r = 64 * wm + 16 * i + er + q;
        size_t row = (size_t)(r >> 5) * NP + n * Pp + (r & 31);
        y[row * Dd + c] = f2b(acc[i][j][q] + bv[j]);
      }
    }
}

// ---------------------------------------------------------------------------
extern "C" void kernel_launch(void* const* d_in, const int* in_sizes, int n_in,
                              void* d_out, int out_size, void* d_ws, size_t ws_size,
                              hipStream_t stream) {
  const float* x    = (const float*)d_in[0];
  const float* phi  = (const float*)d_in[1];
  const float* W    = (const float*)d_in[2];
  const float* bias = (const float*)d_in[3];
  float* out = (float*)d_out;
  char* ws = (char*)d_ws;

  // Non-aliased workspace (~248 MB of the 1 GiB d_ws):
  float*          logits = (float*)(ws);                            // 67.1 MB
  unsigned short* disp_b = (unsigned short*)(ws + 67108864);        // 33.5 MB
  unsigned short* comb_b = (unsigned short*)(ws + 100663296);       // 33.5 MB
  unsigned short* dispT  = (unsigned short*)(ws + 134217728);       // 33.5 MB
  unsigned short* xb     = (unsigned short*)(ws + 167772160);       // 16.8 MB
  unsigned short* xT     = (unsigned short*)(ws + 184549376);       // 16.8 MB
  unsigned short* phiT   = (unsigned short*)(ws + 201326592);       //  4.2 MB
  unsigned short* slots  = (unsigned short*)(ws + 209715200);       // 16.8 MB
  unsigned short* y_b    = (unsigned short*)(ws + 226492416);       // 16.8 MB
  unsigned short* yT     = (unsigned short*)(ws + 243269632);       // 16.8 MB

  k_xprep<<<dim3(32, 64, Bb), 256, 0, stream>>>(x, xb, xT);
  k_tr_f2b<<<dim3(64, 32, 1), 256, 0, stream>>>(phi, phiT, Dd, NP);
  k_gemm<0><<<dim3(16, 64, 1), 256, 0, stream>>>(xb, 0, phiT, 0, logits, 0, BM, NP, Dd);
  k_softmax<<<Mm, 256, 0, stream>>>(logits, disp_b, comb_b);
  k_tr_b2b<<<dim3(64, 64, Bb), 256, 0, stream>>>(disp_b, (size_t)Mm * NP, dispT, (size_t)NP * Mm, Mm, NP);
  k_gemm<1><<<dim3(8, 16, Bb), 256, 0, stream>>>(dispT, (size_t)NP * Mm, xT, (size_t)Dd * Mm,
                                                 slots, (size_t)NP * Dd, NP, Dd, Mm);
  k_y_mfma<<<dim3(8, 1, Nn), 256, 0, stream>>>(slots, W, bias, y_b);
  k_tr_b2b<<<dim3(32, 64, Bb), 256, 0, stream>>>(y_b, (size_t)NP * Dd, yT, (size_t)Dd * NP, NP, Dd);
  k_gemm<0><<<dim3(8, 16, Bb), 256, 0, stream>>>(comb_b, (size_t)Mm * NP, yT, (size_t)Dd * NP,
                                                 out, (size_t)Mm * Dd, Mm, Dd, NP);
}

// Round 4
// 606.140 us; speedup vs baseline: 2.8781x; 1.0347x over previous
//
#include <hip/hip_runtime.h>
#include <hip/hip_bf16.h>
#include <cstddef>

#define Bb 4
#define Mm 2048
#define Dd 1024
#define Nn 64
#define Pp 32
#define NP 2048
#define BM 8192

typedef __attribute__((ext_vector_type(4))) float v4f;
typedef __attribute__((ext_vector_type(8))) short v8s;

__device__ inline unsigned short f2b(float f) {
  union { float f; unsigned u; } v; v.f = f;
  unsigned r = v.u + 0x7fff + ((v.u >> 16) & 1);
  return (unsigned short)(r >> 16);
}

__device__ inline void gld16(const void* g, void* l) {
  __builtin_amdgcn_global_load_lds(
      (const __attribute__((address_space(1))) unsigned*)g,
      (__attribute__((address_space(3))) unsigned*)l, 16, 0, 0);
}

// ---------------------------------------------------------------------------
// k_xprep: one pass over x. Writes xb (bf16, [b][m][d]) and xT (bf16, [b][d][m]).
// ---------------------------------------------------------------------------
__global__ __launch_bounds__(256) void k_xprep(const float* __restrict__ x,
                                               unsigned short* __restrict__ xb,
                                               unsigned short* __restrict__ xT) {
  __shared__ unsigned short t[32][33];
  const int b = blockIdx.z;
  const int r0 = blockIdx.y * 32;   // m
  const int c0 = blockIdx.x * 32;   // d
  const float* ib = x + (size_t)b * Mm * Dd;
  const int tr = threadIdx.x >> 3;
  const int tc = (threadIdx.x & 7) * 4;
  float4 v = *(const float4*)&ib[(size_t)(r0 + tr) * Dd + c0 + tc];
  ushort4 s;
  s.x = f2b(v.x); s.y = f2b(v.y); s.z = f2b(v.z); s.w = f2b(v.w);
  *(ushort4*)&xb[(size_t)b * Mm * Dd + (size_t)(r0 + tr) * Dd + c0 + tc] = s;
  t[tr][tc + 0] = s.x; t[tr][tc + 1] = s.y;
  t[tr][tc + 2] = s.z; t[tr][tc + 3] = s.w;
  __syncthreads();
  ushort4 o;
  o.x = t[tc + 0][tr]; o.y = t[tc + 1][tr];
  o.z = t[tc + 2][tr]; o.w = t[tc + 3][tr];
  *(ushort4*)&xT[(size_t)b * Dd * Mm + (size_t)(c0 + tr) * Mm + r0 + tc] = o;
}

// ---------------------------------------------------------------------------
// tiled transpose fp32 -> bf16 : in [R][C] -> out [C][R] (for phi)
// ---------------------------------------------------------------------------
__global__ __launch_bounds__(256) void k_tr_f2b(const float* __restrict__ in,
                                                unsigned short* __restrict__ out,
                                                int R, int C) {
  __shared__ unsigned short t[32][33];
  const int r0 = blockIdx.y * 32, c0 = blockIdx.x * 32;
  const int tr = threadIdx.x >> 3;
  const int tc = (threadIdx.x & 7) * 4;
  float4 v = *(const float4*)&in[(size_t)(r0 + tr) * C + c0 + tc];
  t[tr][tc + 0] = f2b(v.x); t[tr][tc + 1] = f2b(v.y);
  t[tr][tc + 2] = f2b(v.z); t[tr][tc + 3] = f2b(v.w);
  __syncthreads();
  ushort4 o;
  o.x = t[tc + 0][tr]; o.y = t[tc + 1][tr];
  o.z = t[tc + 2][tr]; o.w = t[tc + 3][tr];
  *(ushort4*)&out[(size_t)(c0 + tr) * R + r0 + tc] = o;
}

// bf16 -> bf16 batched transpose
__global__ __launch_bounds__(256) void k_tr_b2b(const unsigned short* __restrict__ in, size_t sin_,
                                                unsigned short* __restrict__ out, size_t sout,
                                                int R, int C) {
  __shared__ unsigned short t[32][33];
  const int r0 = blockIdx.y * 32, c0 = blockIdx.x * 32;
  const unsigned short* ib = in + (size_t)blockIdx.z * sin_;
  unsigned short* ob = out + (size_t)blockIdx.z * sout;
  const int tr = threadIdx.x >> 3;
  const int tc = (threadIdx.x & 7) * 4;
  ushort4 v = *(const ushort4*)&ib[(size_t)(r0 + tr) * C + c0 + tc];
  t[tr][tc + 0] = v.x; t[tr][tc + 1] = v.y;
  t[tr][tc + 2] = v.z; t[tr][tc + 3] = v.w;
  __syncthreads();
  ushort4 o;
  o.x = t[tc + 0][tr]; o.y = t[tc + 1][tr];
  o.z = t[tc + 2][tr]; o.w = t[tc + 3][tr];
  *(ushort4*)&ob[(size_t)(c0 + tr) * R + r0 + tc] = o;
}

// ---------------------------------------------------------------------------
// bf16 MFMA GEMM, BK=64 dual-buffer: C[M,N] = A[M,K] @ B^T[N,K]
// One barrier pair per 64 K-elements; 32 MFMA between barriers.
// ---------------------------------------------------------------------------
template <int OUT_BF16>
__global__ __launch_bounds__(256) void k_gemm(const unsigned short* __restrict__ A, size_t sA,
                                              const unsigned short* __restrict__ B, size_t sB,
                                              void* __restrict__ C, size_t sC,
                                              int M, int N, int K) {
  __shared__ unsigned short As[2][128][32];
  __shared__ unsigned short Bs[2][128][32];
  const int tid = threadIdx.x;
  const int wv = tid >> 6, ln = tid & 63;
  const int wm = wv & 1, wn = wv >> 1;
  const int row0 = blockIdx.y * 128, col0 = blockIdx.x * 128;
  const unsigned short* Ab = A + (size_t)blockIdx.z * sA + (size_t)row0 * K;
  const unsigned short* Bbp = B + (size_t)blockIdx.z * sB + (size_t)col0 * K;
  const int sr = ln >> 2;
  const int sc = (ln & 3) * 8;
  const int fr = ln & 15, fc = (ln >> 4) * 8;
  v4f acc[4][4];
#pragma unroll
  for (int i = 0; i < 4; ++i)
#pragma unroll
    for (int j = 0; j < 4; ++j) { v4f z = {0.f, 0.f, 0.f, 0.f}; acc[i][j] = z; }

  for (int kt = 0; kt < K; kt += 64) {
    __syncthreads();
    const size_t ga1 = (size_t)(32 * wv + sr) * K + kt + sc;
    const size_t ga2 = (size_t)(32 * wv + 16 + sr) * K + kt + sc;
    gld16(Ab + ga1,       &As[0][32 * wv][0]);
    gld16(Ab + ga2,       &As[0][32 * wv + 16][0]);
    gld16(Ab + ga1 + 32,  &As[1][32 * wv][0]);
    gld16(Ab + ga2 + 32,  &As[1][32 * wv + 16][0]);
    gld16(Bbp + ga1,      &Bs[0][32 * wv][0]);
    gld16(Bbp + ga2,      &Bs[0][32 * wv + 16][0]);
    gld16(Bbp + ga1 + 32, &Bs[1][32 * wv][0]);
    gld16(Bbp + ga2 + 32, &Bs[1][32 * wv + 16][0]);
    __syncthreads();
#pragma unroll
    for (int ks = 0; ks < 2; ++ks) {
      v8s a[4], b[4];
#pragma unroll
      for (int i = 0; i < 4; ++i) a[i] = *(const v8s*)&As[ks][64 * wm + 16 * i + fr][fc];
#pragma unroll
      for (int j = 0; j < 4; ++j) b[j] = *(const v8s*)&Bs[ks][64 * wn + 16 * j + fr][fc];
#pragma unroll
      for (int i = 0; i < 4; ++i)
#pragma unroll
        for (int j = 0; j < 4; ++j)
          acc[i][j] = __builtin_amdgcn_mfma_f32_16x16x32_bf16(a[i], b[j], acc[i][j], 0, 0, 0);
    }
  }
  const int er = (ln >> 4) * 4, ec = ln & 15;
#pragma unroll
  for (int i = 0; i < 4; ++i)
#pragma unroll
    for (int j = 0; j < 4; ++j) {
      int r = row0 + 64 * wm + 16 * i + er;
      int c = col0 + 64 * wn + 16 * j + ec;
      if (OUT_BF16) {
        unsigned short* Cp = (unsigned short*)C + (size_t)blockIdx.z * sC + (size_t)r * N + c;
#pragma unroll
        for (int q = 0; q < 4; ++q) Cp[(size_t)q * N] = f2b(acc[i][j][q]);
      } else {
        float* Cp = (float*)C + (size_t)blockIdx.z * sC + (size_t)r * N + c;
#pragma unroll
        for (int q = 0; q < 4; ++q) Cp[(size_t)q * N] = acc[i][j][q];
      }
    }
}

// ---------------------------------------------------------------------------
// softmaxes (shuffle-reduce). One block per m.
// ---------------------------------------------------------------------------
__global__ __launch_bounds__(256) void k_softmax(const float* __restrict__ logits,
                                                 unsigned short* __restrict__ dispatch,
                                                 unsigned short* __restrict__ combine) {
  __shared__ float sh[Bb][NP];
  __shared__ float redm[Bb][4];
  __shared__ float reds[Bb][4];
  const int m = blockIdx.x;
  const int tid = threadIdx.x;
  const int wv = tid >> 6, ln = tid & 63;
#pragma unroll
  for (int b = 0; b < Bb; ++b) {
    const float4* src = (const float4*)(logits + ((size_t)b * Mm + m) * NP);
#pragma unroll
    for (int it = 0; it < 2; ++it) ((float4*)sh[b])[tid + it * 256] = src[tid + it * 256];
  }
  __syncthreads();
#pragma unroll
  for (int it = 0; it < 8; ++it) {
    int np = tid + it * 256;
    float v0 = sh[0][np], v1 = sh[1][np], v2 = sh[2][np], v3 = sh[3][np];
    float mx = fmaxf(fmaxf(v0, v1), fmaxf(v2, v3));
    float e0 = __expf(v0 - mx), e1 = __expf(v1 - mx);
    float e2 = __expf(v2 - mx), e3 = __expf(v3 - mx);
    float inv = 1.0f / (e0 + e1 + e2 + e3);
    dispatch[((size_t)0 * Mm + m) * NP + np] = f2b(e0 * inv);
    dispatch[((size_t)1 * Mm + m) * NP + np] = f2b(e1 * inv);
    dispatch[((size_t)2 * Mm + m) * NP + np] = f2b(e2 * inv);
    dispatch[((size_t)3 * Mm + m) * NP + np] = f2b(e3 * inv);
  }
#pragma unroll
  for (int b = 0; b < Bb; ++b) {
    float lmax = -3.0e38f;
#pragma unroll
    for (int it = 0; it < 8; ++it) lmax = fmaxf(lmax, sh[b][tid + it * 256]);
#pragma unroll
    for (int o = 32; o > 0; o >>= 1) lmax = fmaxf(lmax, __shfl_xor(lmax, o, 64));
    if (ln == 0) redm[b][wv] = lmax;
    __syncthreads();
    float mx = fmaxf(fmaxf(redm[b][0], redm[b][1]), fmaxf(redm[b][2], redm[b][3]));
    float lsum = 0.0f;
#pragma unroll
    for (int it = 0; it < 8; ++it) lsum += __expf(sh[b][tid + it * 256] - mx);
#pragma unroll
    for (int o = 32; o > 0; o >>= 1) lsum += __shfl_xor(lsum, o, 64);
    if (ln == 0) reds[b][wv] = lsum;
    __syncthreads();
    float inv = 1.0f / (reds[b][0] + reds[b][1] + reds[b][2] + reds[b][3]);
#pragma unroll
    for (int it = 0; it < 8; ++it) {
      int np = tid + it * 256;
      combine[((size_t)b * Mm + m) * NP + np] = f2b(__expf(sh[b][np] - mx) * inv);
    }
  }
}

// ---------------------------------------------------------------------------
// k_y: per expert n, BK=64 dual-buffer. A (slots) via gld16; W fp32 staged
// through VALU cvt into padded LDS.
// ---------------------------------------------------------------------------
__global__ __launch_bounds__(256) void k_y_mfma(const unsigned short* __restrict__ slots,
                                                const float* __restrict__ W,
                                                const float* __restrict__ bias,
                                                unsigned short* __restrict__ y) {
  __shared__ unsigned short As[2][128][32];
  __shared__ unsigned short Bs[2][128][40];
  const int n = blockIdx.z;
  const int col0 = blockIdx.x * 128;
  const int tid = threadIdx.x;
  const int wv = tid >> 6, ln = tid & 63;
  const int wm = wv & 1, wn = wv >> 1;
  const int sr = ln >> 2, sc = (ln & 3) * 8;
  const int fr = ln & 15, fc = (ln >> 4) * 8;
  const float* Wn = W + (size_t)n * Dd * Dd;
  v4f acc[4][4];
#pragma unroll
  for (int i = 0; i < 4; ++i)
#pragma unroll
    for (int j = 0; j < 4; ++j) { v4f z = {0.f, 0.f, 0.f, 0.f}; acc[i][j] = z; }

  for (int kt = 0; kt < Dd; kt += 64) {
    __syncthreads();
    {
      int r1 = 32 * wv + sr;
      int r2 = r1 + 16;
      size_t g1 = ((size_t)(r1 >> 5) * NP + n * Pp + (r1 & 31)) * Dd + kt + sc;
      size_t g2 = ((size_t)(r2 >> 5) * NP + n * Pp + (r2 & 31)) * Dd + kt + sc;
      gld16(slots + g1,      &As[0][32 * wv][0]);
      gld16(slots + g2,      &As[0][32 * wv + 16][0]);
      gld16(slots + g1 + 32, &As[1][32 * wv][0]);
      gld16(slots + g2 + 32, &As[1][32 * wv + 16][0]);
    }
#pragma unroll
    for (int buf = 0; buf < 2; ++buf) {
#pragma unroll
      for (int it = 0; it < 2; ++it) {
        int idx = tid + it * 256;
        int k = (idx >> 5) * 2;
        int eseg = (idx & 31) * 4;
        const float* wp = &Wn[(size_t)(kt + buf * 32 + k) * Dd + col0 + eseg];
        float4 r0 = *(const float4*)wp;
        float4 r1 = *(const float4*)(wp + Dd);
        *(__hip_bfloat162*)&Bs[buf][eseg + 0][k] = __float22bfloat162_rn(float2{r0.x, r1.x});
        *(__hip_bfloat162*)&Bs[buf][eseg + 1][k] = __float22bfloat162_rn(float2{r0.y, r1.y});
        *(__hip_bfloat162*)&Bs[buf][eseg + 2][k] = __float22bfloat162_rn(float2{r0.z, r1.z});
        *(__hip_bfloat162*)&Bs[buf][eseg + 3][k] = __float22bfloat162_rn(float2{r0.w, r1.w});
      }
    }
    __syncthreads();
#pragma unroll
    for (int ks = 0; ks < 2; ++ks) {
      v8s a[4], b[4];
#pragma unroll
      for (int i = 0; i < 4; ++i) a[i] = *(const v8s*)&As[ks][64 * wm + 16 * i + fr][fc];
#pragma unroll
      for (int j = 0; j < 4; ++j) b[j] = *(const v8s*)&Bs[ks][64 * wn + 16 * j + fr][fc];
#pragma unroll
      for (int i = 0; i < 4; ++i)
#pragma unroll
        for (int j = 0; j < 4; ++j)
          acc[i][j] = __builtin_amdgcn_mfma_f32_16x16x32_bf16(a[i], b[j], acc[i][j], 0, 0, 0);
    }
  }
  const int er = (ln >> 4) * 4, ec = ln & 15;
  float bv[4];
#pragma unroll
  for (int j = 0; j < 4; ++j) bv[j] = bias[(size_t)n * Dd + col0 + 64 * wn + 16 * j + ec];
#pragma unroll
  for (int i = 0; i < 4; ++i)
#pragma unroll
    for (int j = 0; j < 4; ++j) {
      int c = col0 + 64 * wn + 16 * j + ec;
#pragma unroll
      for (int q = 0; q < 4; ++q) {
        int r = 64 * wm + 16 * i + er + q;
        size_t row = (size_t)(r >> 5) * NP + n * Pp + (r & 31);
        y[row * Dd + c] = f2b(acc[i][j][q] + bv[j]);
      }
    }
}

// ---------------------------------------------------------------------------
extern "C" void kernel_launch(void* const* d_in, const int* in_sizes, int n_in,
                              void* d_out, int out_size, void* d_ws, size_t ws_size,
                              hipStream_t stream) {
  const float* x    = (const float*)d_in[0];
  const float* phi  = (const float*)d_in[1];
  const float* W    = (const float*)d_in[2];
  const float* bias = (const float*)d_in[3];
  float* out = (float*)d_out;
  char* ws = (char*)d_ws;

  float*          logits = (float*)(ws);                            // 67.1 MB
  unsigned short* disp_b = (unsigned short*)(ws + 67108864);        // 33.5 MB
  unsigned short* comb_b = (unsigned short*)(ws + 100663296);       // 33.5 MB
  unsigned short* dispT  = (unsigned short*)(ws + 134217728);       // 33.5 MB
  unsigned short* xb     = (unsigned short*)(ws + 167772160);       // 16.8 MB
  unsigned short* xT     = (unsigned short*)(ws + 184549376);       // 16.8 MB
  unsigned short* phiT   = (unsigned short*)(ws + 201326592);       //  4.2 MB
  unsigned short* slots  = (unsigned short*)(ws + 209715200);       // 16.8 MB
  unsigned short* y_b    = (unsigned short*)(ws + 226492416);       // 16.8 MB
  unsigned short* yT     = (unsigned short*)(ws + 243269632);       // 16.8 MB

  k_xprep<<<dim3(32, 64, Bb), 256, 0, stream>>>(x, xb, xT);
  k_tr_f2b<<<dim3(64, 32, 1), 256, 0, stream>>>(phi, phiT, Dd, NP);
  k_gemm<0><<<dim3(16, 64, 1), 256, 0, stream>>>(xb, 0, phiT, 0, logits, 0, BM, NP, Dd);
  k_softmax<<<Mm, 256, 0, stream>>>(logits, disp_b, comb_b);
  k_tr_b2b<<<dim3(64, 64, Bb), 256, 0, stream>>>(disp_b, (size_t)Mm * NP, dispT, (size_t)NP * Mm, Mm, NP);
  k_gemm<1><<<dim3(8, 16, Bb), 256, 0, stream>>>(dispT, (size_t)NP * Mm, xT, (size_t)Dd * Mm,
                                                 slots, (size_t)NP * Dd, NP, Dd, Mm);
  k_y_mfma<<<dim3(8, 1, Nn), 256, 0, stream>>>(slots, W, bias, y_b);
  k_tr_b2b<<<dim3(32, 64, Bb), 256, 0, stream>>>(y_b, (size_t)NP * Dd, yT, (size_t)Dd * NP, NP, Dd);
  k_gemm<0><<<dim3(8, 16, Bb), 256, 0, stream>>>(comb_b, (size_t)Mm * NP, yT, (size_t)Dd * NP,
                                                 out, (size_t)Mm * Dd, Mm, Dd, NP);
}